// Round 13
// baseline (1132.976 us; speedup 1.0000x reference)
//
#include <hip/hip_runtime.h>
#include <hip/hip_fp16.h>

#define NN 100000
#define NE 1200000
#define DIM 64
#define QF 16                     // features per quarter-plane
#define NQ 4
#define NBINS 391                 // bin = dst >> 8  (256 nodes per bin)
#define NBE 128                   // edge-partition blocks
#define CHUNK (NE / NBE)          // 9375, exact
#define NBLK ((NN + 255) / 256)   // 391 scan blocks
#define NPH 7                     // src phases, phase = src >> 14

// out = sc[d]*y + bx[d] + sum_e w_e * Y[src_e]   (feature-wise independent!)
//   sc = 0.5625 - 0.5*rD ; bx = 0.5*rD*x
//   w = nsc_g[dst] * rsqrt(deg_g[src]),  nsc = (+0.5*inv0, -0.0625*inv1)
// Y fp16 mirror stored as 4 planes of [NN][16] -> 3.2 MB gather working set
// binned record (4B): [dstLow:8|g:1|src:17]
// es edge record (4B): [w_fp16_hi15:15|src:17], per-node lists padded to x16

__global__ void __launch_bounds__(256) bin_count(const int* __restrict__ dst0,
                                                 const int* __restrict__ dst1,
                                                 int* __restrict__ blk_cnt) {
    __shared__ int c[NBINS];
    int t = threadIdx.x;
    for (int i = t; i < NBINS; i += 256) c[i] = 0;
    __syncthreads();
    int lo = blockIdx.x * CHUNK, hi = lo + CHUNK;
    for (int e = lo + t; e < hi; e += 256) {
        atomicAdd(&c[dst0[e] >> 8], 1);
        atomicAdd(&c[dst1[e] >> 8], 1);
    }
    __syncthreads();
    for (int i = t; i < NBINS; i += 256) blk_cnt[blockIdx.x * NBINS + i] = c[i];
}

__global__ void __launch_bounds__(512) bin_scan(const int* __restrict__ blk_cnt,
                                                int* __restrict__ bin_start) {
    __shared__ int tot[512];
    int t = threadIdx.x;
    int s = 0;
    if (t < NBINS)
        for (int b = 0; b < NBE; ++b) s += blk_cnt[b * NBINS + t];
    tot[t] = s;
    __syncthreads();
    for (int off = 1; off < 512; off <<= 1) {
        int v = (t >= off) ? tot[t - off] : 0;
        __syncthreads();
        tot[t] += v;
        __syncthreads();
    }
    if (t <= NBINS) bin_start[t] = tot[t] - s;
}

__global__ void __launch_bounds__(NBE) blk_base_k(const int* __restrict__ blk_cnt,
                                                  const int* __restrict__ bin_start,
                                                  int* __restrict__ blk_base) {
    __shared__ int s[NBE];
    int b = blockIdx.x, t = threadIdx.x;
    int v = blk_cnt[t * NBINS + b];
    s[t] = v;
    __syncthreads();
    for (int off = 1; off < NBE; off <<= 1) {
        int x = (t >= off) ? s[t - off] : 0;
        __syncthreads();
        s[t] += x;
        __syncthreads();
    }
    blk_base[t * NBINS + b] = bin_start[b] + s[t] - v;
}

__global__ void __launch_bounds__(256) bin_permute(const int* __restrict__ src0,
                                                   const int* __restrict__ dst0,
                                                   const int* __restrict__ src1,
                                                   const int* __restrict__ dst1,
                                                   const int* __restrict__ blk_base,
                                                   unsigned int* __restrict__ binned) {
    __shared__ int off[NBINS];
    int t = threadIdx.x;
    for (int i = t; i < NBINS; i += 256) off[i] = blk_base[blockIdx.x * NBINS + i];
    __syncthreads();
    int lo = blockIdx.x * CHUNK, hi = lo + CHUNK;
    for (int e = lo + t; e < hi; e += 256) {
        int s = src0[e], d = dst0[e];
        int p = atomicAdd(&off[d >> 8], 1);
        binned[p] = (unsigned)s | ((unsigned)(d & 255) << 18);
        s = src1[e]; d = dst1[e];
        p = atomicAdd(&off[d >> 8], 1);
        binned[p] = (unsigned)s | (1u << 17) | ((unsigned)(d & 255) << 18);
    }
}

__global__ void __launch_bounds__(256) deg_count(const unsigned int* __restrict__ binned,
                                                 const int* __restrict__ bin_start,
                                                 int* __restrict__ deg0,
                                                 int* __restrict__ deg1) {
    __shared__ int dg[512];
    int b = blockIdx.x, t = threadIdx.x;
    dg[t] = 0; dg[t + 256] = 0;
    __syncthreads();
    int lo = bin_start[b], hi = bin_start[b + 1];
    for (int i = lo + t; i < hi; i += 256) {
        unsigned r = binned[i];
        int dlow = (r >> 18) & 255, g = (r >> 17) & 1;
        atomicAdd(&dg[(dlow << 1) | g], 1);
    }
    __syncthreads();
    int n = b * 256 + t;
    if (n < NN) { deg0[n] = dg[t << 1]; deg1[n] = dg[(t << 1) | 1]; }
}

__global__ void __launch_bounds__(256) scan_l1(const int* __restrict__ deg0,
                                               const int* __restrict__ deg1,
                                               int* __restrict__ rs, int* __restrict__ dp,
                                               int* __restrict__ bs) {
    __shared__ int s0[256];
    int t = threadIdx.x;
    int n = blockIdx.x * 256 + t;
    int a = 0;
    if (n < NN) a = (deg0[n] + deg1[n] + 15) & ~15;   // pad to x16
    s0[t] = a;
    __syncthreads();
    for (int off = 1; off < 256; off <<= 1) {
        int x0 = (t >= off) ? s0[t - off] : 0;
        __syncthreads();
        s0[t] += x0;
        __syncthreads();
    }
    if (n < NN) { rs[n] = s0[t] - a; dp[n] = a; }
    if (t == 255) bs[blockIdx.x] = s0[255];
}

__global__ void __launch_bounds__(512) scan_l2(int* __restrict__ bs) {
    __shared__ int s0[512];
    int t = threadIdx.x;
    int a = (t < NBLK) ? bs[t] : 0;
    s0[t] = a;
    __syncthreads();
    for (int off = 1; off < 512; off <<= 1) {
        int x0 = (t >= off) ? s0[t - off] : 0;
        __syncthreads();
        s0[t] += x0;
        __syncthreads();
    }
    if (t < NBLK) bs[t] = s0[t] - a;
}

__global__ void __launch_bounds__(256) scan_l3(int* __restrict__ rs, const int* __restrict__ bs) {
    int n = blockIdx.x * 256 + threadIdx.x;
    if (n < NN) rs[n] += bs[blockIdx.x];
}

__global__ void node_params(const int* __restrict__ deg0, const int* __restrict__ deg1,
                            float2* __restrict__ nsc, float* __restrict__ sc,
                            float* __restrict__ cy) {
    int n = blockIdx.x * blockDim.x + threadIdx.x;
    if (n < NN) {
        int a = deg0[n], b = deg1[n];
        nsc[n] = make_float2((a > 0) ? 0.5f * rsqrtf((float)a) : 0.0f,
                             (b > 0) ? -0.0625f * rsqrtf((float)b) : 0.0f);
        int s = a + b;
        float rD = (s > 0) ? 1.0f / (float)s : 0.0f;
        sc[n] = 0.5625f - 0.5f * rD;
        cy[n] = 0.5f * rD;
    }
}

__global__ void __launch_bounds__(256) csr_scatter(const unsigned int* __restrict__ binned,
                                                   const int* __restrict__ bin_start,
                                                   const int* __restrict__ rs,
                                                   const int* __restrict__ deg0,
                                                   const int* __restrict__ deg1,
                                                   const float2* __restrict__ nsc,
                                                   int* __restrict__ es) {
    __shared__ int hist[8 * 256];
    __shared__ int rsl[256];
    __shared__ int degsum[256];
    __shared__ float2 nscl[256];
    __shared__ float lutw[128];
    int b = blockIdx.x, t = threadIdx.x;
    int n = b * 256 + t;
    rsl[t]  = (n < NN) ? rs[n] : 0;
    nscl[t] = (n < NN) ? nsc[n] : make_float2(0.0f, 0.0f);
    if (t < 128) lutw[t] = (t == 0) ? 0.0f : rsqrtf((float)t);
    for (int i = t; i < 8 * 256; i += 256) hist[i] = 0;
    __syncthreads();
    int lo = bin_start[b], hi = bin_start[b + 1];
    for (int i = lo + t; i < hi; i += 256) {
        unsigned r = binned[i];
        int ph = (r & 0x1FFFF) >> 14;
        atomicAdd(&hist[ph * 256 + ((r >> 18) & 255)], 1);
    }
    __syncthreads();
    {
        int acc = 0;
        for (int ph = 0; ph < NPH; ++ph) {
            int v = hist[ph * 256 + t];
            hist[ph * 256 + t] = acc;
            acc += v;
        }
        degsum[t] = acc;
    }
    __syncthreads();
    for (int i = lo + t; i < hi; i += 256) {
        unsigned r = binned[i];
        int sN = r & 0x1FFFF, g = (r >> 17) & 1, dlow = (r >> 18) & 255;
        int ph = sN >> 14;
        int p = atomicAdd(&hist[ph * 256 + dlow], 1);
        int dgv = g ? deg1[sN] : deg0[sN];
        float2 nn = nscl[dlow];
        float wf = (g ? nn.y : nn.x) * lutw[dgv & 127];
        unsigned u = (unsigned)__half_as_ushort(__float2half(wf));
        es[rsl[dlow] + p] = (int)((((u + 1u) >> 1) << 17) | (unsigned)sN);
    }
    __syncthreads();
    if (n < NN) {
        int base = rsl[t], ds = degsum[t], dpv = (ds + 15) & ~15;
        for (int i = base + ds; i < base + dpv; ++i) es[i] = 0;  // w=+0, src=0
    }
}

// x -> 4 quarter-planes of fp16 (HA) and pre-scaled BX planes.
__global__ void convert_x(const float* __restrict__ X, const float* __restrict__ cy,
                          __half* __restrict__ HA, __half* __restrict__ BX) {
    int i = blockIdx.x * blockDim.x + threadIdx.x;   // one ushort4 (4 features)
    if (i < NN * 16) {
        int n = i >> 4, j = i & 15;                  // j = feature-group 0..15
        float4 v = ((const float4*)X)[i];
        float c = cy[n];
        size_t dsti = (size_t)(j >> 2) * NN * QF + (size_t)n * QF + (j & 3) * 4;
        ushort4 a, b;
        a.x = __half_as_ushort(__float2half(v.x));
        a.y = __half_as_ushort(__float2half(v.y));
        a.z = __half_as_ushort(__float2half(v.z));
        a.w = __half_as_ushort(__float2half(v.w));
        b.x = __half_as_ushort(__float2half(v.x * c));
        b.y = __half_as_ushort(__float2half(v.y * c));
        b.z = __half_as_ushort(__float2half(v.z * c));
        b.w = __half_as_ushort(__float2half(v.w * c));
        *(ushort4*)(HA + dsti) = a;
        *(ushort4*)(BX + dsti) = b;
    }
}

__device__ __forceinline__ float4 h4f(ushort4 v) {
    return make_float4(__half2float(__ushort_as_half(v.x)),
                       __half2float(__ushort_as_half(v.y)),
                       __half2float(__ushort_as_half(v.z)),
                       __half2float(__ushort_as_half(v.w)));
}

__device__ __forceinline__ float wdec(int r) {
    return __half2float(__ushort_as_half((unsigned short)(((unsigned)r >> 16) & 0xFFFEu)));
}

// Quarter-sliced step. quarter q = blockIdx.x / (NN/4): gathers touch ONLY
// plane q (3.2 MB -> L2-resident per XCD). Wave: sub = lane>>2 (16 edge
// slots), fl = lane&3 (features 4fl..4fl+3 of the quarter). One 8B gather
// per lane covers 16 rows/instruction. 2-deep pipeline.
__global__ void __launch_bounds__(256) step_kernel(
    const __half* __restrict__ Yh, const __half* __restrict__ BXq,
    const int* __restrict__ rs, const int* __restrict__ dp,
    const int* __restrict__ es, const float* __restrict__ sc,
    __half* __restrict__ Yho, float* __restrict__ Ffo)
{
    const int bpq = NN / 4;                 // 25000 blocks per quarter
    int q  = blockIdx.x / bpq;
    int nb = blockIdx.x - q * bpq;
    int node = nb * 4 + (threadIdx.x >> 6);
    int lane = threadIdx.x & 63;
    int sub  = lane >> 2;
    int fl   = lane & 3;
    int un = __builtin_amdgcn_readfirstlane(node);
    int s  = __builtin_amdgcn_readfirstlane(rs[un]);
    int c  = __builtin_amdgcn_readfirstlane(dp[un]);

    const __half* Yq = Yh + (size_t)q * NN * QF;
    const int* ep = es + s + sub;

    float4 acc = make_float4(0.0f, 0.0f, 0.0f, 0.0f);
    int rA = ep[0];
    int rB = ep[16];
    ushort4 gA = *(const ushort4*)(Yq + (size_t)(rA & 0x1FFFF) * QF + 4 * fl);
    for (int i = 0; i < c; i += 16) {
        int rC = ep[i + 32];                 // slack-covered
        ushort4 gB = *(const ushort4*)(Yq + (size_t)(rB & 0x1FFFF) * QF + 4 * fl);
        float w = wdec(rA);
        float4 f = h4f(gA);
        acc.x = fmaf(f.x, w, acc.x);
        acc.y = fmaf(f.y, w, acc.y);
        acc.z = fmaf(f.z, w, acc.z);
        acc.w = fmaf(f.w, w, acc.w);
        rA = rB; rB = rC; gA = gB;
    }
    // reduce over the 16 sub-slots (lane bits 2..5)
    acc.x += __shfl_xor(acc.x, 4);  acc.x += __shfl_xor(acc.x, 8);
    acc.x += __shfl_xor(acc.x, 16); acc.x += __shfl_xor(acc.x, 32);
    acc.y += __shfl_xor(acc.y, 4);  acc.y += __shfl_xor(acc.y, 8);
    acc.y += __shfl_xor(acc.y, 16); acc.y += __shfl_xor(acc.y, 32);
    acc.z += __shfl_xor(acc.z, 4);  acc.z += __shfl_xor(acc.z, 8);
    acc.z += __shfl_xor(acc.z, 16); acc.z += __shfl_xor(acc.z, 32);
    acc.w += __shfl_xor(acc.w, 4);  acc.w += __shfl_xor(acc.w, 8);
    acc.w += __shfl_xor(acc.w, 16); acc.w += __shfl_xor(acc.w, 32);

    if (sub == 0) {
        size_t qi = (size_t)q * NN * QF + (size_t)un * QF + 4 * fl;
        float4 y  = h4f(*(const ushort4*)(Yh + qi));
        float4 bx = h4f(*(const ushort4*)(BXq + qi));
        float scl = sc[un];
        float o0 = fmaf(scl, y.x, bx.x) + acc.x;
        float o1 = fmaf(scl, y.y, bx.y) + acc.y;
        float o2 = fmaf(scl, y.z, bx.z) + acc.z;
        float o3 = fmaf(scl, y.w, bx.w) + acc.w;
        if (Ffo) {
            *(float4*)(Ffo + (size_t)un * DIM + q * QF + 4 * fl) =
                make_float4(o0, o1, o2, o3);
        } else {
            ushort4 ov;
            ov.x = __half_as_ushort(__float2half(o0));
            ov.y = __half_as_ushort(__float2half(o1));
            ov.z = __half_as_ushort(__float2half(o2));
            ov.w = __half_as_ushort(__float2half(o3));
            *(ushort4*)(Yho + qi) = ov;
        }
    }
}

extern "C" void kernel_launch(void* const* d_in, const int* in_sizes, int n_in,
                              void* d_out, int out_size, void* d_ws, size_t ws_size,
                              hipStream_t stream) {
    const float* x   = (const float*)d_in[0];
    const int* src0  = (const int*)d_in[1];
    const int* dst0  = (const int*)d_in[2];
    const int* src1  = (const int*)d_in[3];
    const int* dst1  = (const int*)d_in[4];
    float* out = (float*)d_out;

    char* ws = (char*)d_ws;
    size_t off = 0;
    auto alloc = [&](size_t bytes) -> void* {
        void* p = ws + off;
        off += (bytes + 255) & ~(size_t)255;
        return p;
    };

    const size_t ES_CAP = (size_t)2 * NE + 16 * NN + 256;  // x16-padded CSR + slack

    __half* HA   = (__half*)alloc((size_t)NN * DIM * 2);   // 4 quarter-planes
    __half* HB   = (__half*)alloc((size_t)NN * DIM * 2);
    __half* BX   = (__half*)alloc((size_t)NN * DIM * 2);
    unsigned int* binned = (unsigned int*)alloc((size_t)2 * NE * 4);
    int*    es   = (int*)alloc(ES_CAP * 4);
    int*    blk_cnt  = (int*)alloc((size_t)NBE * NBINS * 4);
    int*    blk_base = (int*)alloc((size_t)NBE * NBINS * 4);
    int*    bin_st   = (int*)alloc((size_t)(NBINS + 1) * 4);
    int*    deg0 = (int*)alloc((size_t)NN * 4);
    int*    deg1 = (int*)alloc((size_t)NN * 4);
    int*    rs   = (int*)alloc((size_t)NN * 4);
    int*    dp   = (int*)alloc((size_t)NN * 4);
    float2* nsc  = (float2*)alloc((size_t)NN * 8);
    float*  sc   = (float*)alloc((size_t)NN * 4);
    float*  cy   = (float*)alloc((size_t)NN * 4);
    int*    bs   = (int*)alloc((size_t)NBLK * 4);

    const int TB = 256;
    bin_count<<<NBE, 256, 0, stream>>>(dst0, dst1, blk_cnt);
    bin_scan<<<1, 512, 0, stream>>>(blk_cnt, bin_st);
    blk_base_k<<<NBINS, NBE, 0, stream>>>(blk_cnt, bin_st, blk_base);
    bin_permute<<<NBE, 256, 0, stream>>>(src0, dst0, src1, dst1, blk_base, binned);
    deg_count<<<NBINS, 256, 0, stream>>>(binned, bin_st, deg0, deg1);
    scan_l1<<<NBLK, 256, 0, stream>>>(deg0, deg1, rs, dp, bs);
    scan_l2<<<1, 512, 0, stream>>>(bs);
    scan_l3<<<NBLK, 256, 0, stream>>>(rs, bs);
    node_params<<<(NN + TB - 1) / TB, TB, 0, stream>>>(deg0, deg1, nsc, sc, cy);
    csr_scatter<<<NBINS, 256, 0, stream>>>(binned, bin_st, rs, deg0, deg1, nsc, es);
    convert_x<<<(NN * 16 + TB - 1) / TB, TB, 0, stream>>>(x, cy, HA, BX);

    int grid = (NN / 4) * NQ;   // 25000 blocks per quarter x 4 quarters
    for (int i = 0; i < 8; ++i) {
        const __half* hin = (i & 1) ? HB : HA;
        __half* hout = (i & 1) ? HA : HB;
        float* fout = (i == 7) ? out : nullptr;
        step_kernel<<<grid, TB, 0, stream>>>(hin, BX, rs, dp, es, sc, hout, fout);
    }
}

// Round 14
// 489.946 us; speedup vs baseline: 2.3125x; 2.3125x over previous
//
#include <hip/hip_runtime.h>
#include <hip/hip_fp16.h>

#define NN 100000
#define NE 1200000
#define DIM 64
#define NBINS 391                 // bin = dst >> 8  (256 nodes per bin)
#define NBE 128                   // edge-partition blocks
#define CHUNK (NE / NBE)          // 9375, exact
#define NBLK ((NN + 255) / 256)   // 391 scan blocks
#define NPH 7                     // src phases, phase = src >> 14

// out = sc[d]*y + bx[d] + sum_e w_e * Y[src_e]
//   sc = 0.5625 - 0.5*rD ; bx = 0.5*rD*x
//   w = nsc_g[dst] * rsqrt(deg_g[src]),  nsc = (+0.5*inv0, -0.0625*inv1)
// binned record (4B): [dstLow:8|g:1|src:17]   (dst = bin*256 + dstLow)
// es edge record (4B): [w_fp16_hi15:15|src:17]  (w LSB dropped, round-nearest)

__global__ void __launch_bounds__(256) bin_count(const int* __restrict__ dst0,
                                                 const int* __restrict__ dst1,
                                                 int* __restrict__ blk_cnt) {
    __shared__ int c[NBINS];
    int t = threadIdx.x;
    for (int i = t; i < NBINS; i += 256) c[i] = 0;
    __syncthreads();
    int lo = blockIdx.x * CHUNK, hi = lo + CHUNK;
    for (int e = lo + t; e < hi; e += 256) {
        atomicAdd(&c[dst0[e] >> 8], 1);
        atomicAdd(&c[dst1[e] >> 8], 1);
    }
    __syncthreads();
    for (int i = t; i < NBINS; i += 256) blk_cnt[blockIdx.x * NBINS + i] = c[i];
}

__global__ void __launch_bounds__(512) bin_scan(const int* __restrict__ blk_cnt,
                                                int* __restrict__ bin_start) {
    __shared__ int tot[512];
    int t = threadIdx.x;
    int s = 0;
    if (t < NBINS)
        for (int b = 0; b < NBE; ++b) s += blk_cnt[b * NBINS + t];
    tot[t] = s;
    __syncthreads();
    for (int off = 1; off < 512; off <<= 1) {
        int v = (t >= off) ? tot[t - off] : 0;
        __syncthreads();
        tot[t] += v;
        __syncthreads();
    }
    if (t <= NBINS) bin_start[t] = tot[t] - s;
}

__global__ void __launch_bounds__(NBE) blk_base_k(const int* __restrict__ blk_cnt,
                                                  const int* __restrict__ bin_start,
                                                  int* __restrict__ blk_base) {
    __shared__ int s[NBE];
    int b = blockIdx.x, t = threadIdx.x;
    int v = blk_cnt[t * NBINS + b];
    s[t] = v;
    __syncthreads();
    for (int off = 1; off < NBE; off <<= 1) {
        int x = (t >= off) ? s[t - off] : 0;
        __syncthreads();
        s[t] += x;
        __syncthreads();
    }
    blk_base[t * NBINS + b] = bin_start[b] + s[t] - v;
}

__global__ void __launch_bounds__(256) bin_permute(const int* __restrict__ src0,
                                                   const int* __restrict__ dst0,
                                                   const int* __restrict__ src1,
                                                   const int* __restrict__ dst1,
                                                   const int* __restrict__ blk_base,
                                                   unsigned int* __restrict__ binned) {
    __shared__ int off[NBINS];
    int t = threadIdx.x;
    for (int i = t; i < NBINS; i += 256) off[i] = blk_base[blockIdx.x * NBINS + i];
    __syncthreads();
    int lo = blockIdx.x * CHUNK, hi = lo + CHUNK;
    for (int e = lo + t; e < hi; e += 256) {
        int s = src0[e], d = dst0[e];
        int p = atomicAdd(&off[d >> 8], 1);
        binned[p] = (unsigned)s | ((unsigned)(d & 255) << 18);
        s = src1[e]; d = dst1[e];
        p = atomicAdd(&off[d >> 8], 1);
        binned[p] = (unsigned)s | (1u << 17) | ((unsigned)(d & 255) << 18);
    }
}

__global__ void __launch_bounds__(256) deg_count(const unsigned int* __restrict__ binned,
                                                 const int* __restrict__ bin_start,
                                                 int* __restrict__ deg0,
                                                 int* __restrict__ deg1) {
    __shared__ int dg[512];
    int b = blockIdx.x, t = threadIdx.x;
    dg[t] = 0; dg[t + 256] = 0;
    __syncthreads();
    int lo = bin_start[b], hi = bin_start[b + 1];
    for (int i = lo + t; i < hi; i += 256) {
        unsigned r = binned[i];
        int dlow = (r >> 18) & 255, g = (r >> 17) & 1;
        atomicAdd(&dg[(dlow << 1) | g], 1);
    }
    __syncthreads();
    int n = b * 256 + t;
    if (n < NN) { deg0[n] = dg[t << 1]; deg1[n] = dg[(t << 1) | 1]; }
}

__global__ void __launch_bounds__(256) scan_l1(const int* __restrict__ deg0,
                                               const int* __restrict__ deg1,
                                               int* __restrict__ rs, int* __restrict__ dp,
                                               int* __restrict__ bs) {
    __shared__ int s0[256];
    int t = threadIdx.x;
    int n = blockIdx.x * 256 + t;
    int a = 0;
    if (n < NN) a = (deg0[n] + deg1[n] + 7) & ~7;
    s0[t] = a;
    __syncthreads();
    for (int off = 1; off < 256; off <<= 1) {
        int x0 = (t >= off) ? s0[t - off] : 0;
        __syncthreads();
        s0[t] += x0;
        __syncthreads();
    }
    if (n < NN) { rs[n] = s0[t] - a; dp[n] = a; }
    if (t == 255) bs[blockIdx.x] = s0[255];
}

__global__ void __launch_bounds__(512) scan_l2(int* __restrict__ bs) {
    __shared__ int s0[512];
    int t = threadIdx.x;
    int a = (t < NBLK) ? bs[t] : 0;
    s0[t] = a;
    __syncthreads();
    for (int off = 1; off < 512; off <<= 1) {
        int x0 = (t >= off) ? s0[t - off] : 0;
        __syncthreads();
        s0[t] += x0;
        __syncthreads();
    }
    if (t < NBLK) bs[t] = s0[t] - a;
}

__global__ void __launch_bounds__(256) scan_l3(int* __restrict__ rs, const int* __restrict__ bs) {
    int n = blockIdx.x * 256 + threadIdx.x;
    if (n < NN) rs[n] += bs[blockIdx.x];
}

__global__ void node_params(const int* __restrict__ deg0, const int* __restrict__ deg1,
                            float2* __restrict__ nsc, float* __restrict__ sc,
                            float* __restrict__ cy) {
    int n = blockIdx.x * blockDim.x + threadIdx.x;
    if (n < NN) {
        int a = deg0[n], b = deg1[n];
        nsc[n] = make_float2((a > 0) ? 0.5f * rsqrtf((float)a) : 0.0f,
                             (b > 0) ? -0.0625f * rsqrtf((float)b) : 0.0f);
        int s = a + b;
        float rD = (s > 0) ? 1.0f / (float)s : 0.0f;
        sc[n] = 0.5625f - 0.5f * rD;
        cy[n] = 0.5f * rD;
    }
}

// One block per bin, 2 passes: LDS (phase,node) histogram -> per-node scan ->
// phase-sorted scatter with pre-folded fp15 weights. rsqrt(deg) via LDS LUT.
__global__ void __launch_bounds__(256) csr_scatter(const unsigned int* __restrict__ binned,
                                                   const int* __restrict__ bin_start,
                                                   const int* __restrict__ rs,
                                                   const int* __restrict__ deg0,
                                                   const int* __restrict__ deg1,
                                                   const float2* __restrict__ nsc,
                                                   int* __restrict__ es) {
    __shared__ int hist[8 * 256];
    __shared__ int rsl[256];
    __shared__ int degsum[256];
    __shared__ float2 nscl[256];
    __shared__ float lutw[128];
    int b = blockIdx.x, t = threadIdx.x;
    int n = b * 256 + t;
    rsl[t]  = (n < NN) ? rs[n] : 0;
    nscl[t] = (n < NN) ? nsc[n] : make_float2(0.0f, 0.0f);
    if (t < 128) lutw[t] = (t == 0) ? 0.0f : rsqrtf((float)t);
    for (int i = t; i < 8 * 256; i += 256) hist[i] = 0;
    __syncthreads();
    int lo = bin_start[b], hi = bin_start[b + 1];
    for (int i = lo + t; i < hi; i += 256) {
        unsigned r = binned[i];
        int ph = (r & 0x1FFFF) >> 14;
        atomicAdd(&hist[ph * 256 + ((r >> 18) & 255)], 1);
    }
    __syncthreads();
    {
        int acc = 0;
        for (int ph = 0; ph < NPH; ++ph) {
            int v = hist[ph * 256 + t];
            hist[ph * 256 + t] = acc;
            acc += v;
        }
        degsum[t] = acc;
    }
    __syncthreads();
    for (int i = lo + t; i < hi; i += 256) {
        unsigned r = binned[i];
        int sN = r & 0x1FFFF, g = (r >> 17) & 1, dlow = (r >> 18) & 255;
        int ph = sN >> 14;
        int p = atomicAdd(&hist[ph * 256 + dlow], 1);
        int dgv = g ? deg1[sN] : deg0[sN];
        float2 nn = nscl[dlow];
        float wf = (g ? nn.y : nn.x) * lutw[dgv & 127];
        unsigned u = (unsigned)__half_as_ushort(__float2half(wf));
        es[rsl[dlow] + p] = (int)((((u + 1u) >> 1) << 17) | (unsigned)sN);
    }
    __syncthreads();
    if (n < NN) {
        int base = rsl[t], ds = degsum[t], dpv = (ds + 7) & ~7;
        for (int i = base + ds; i < base + dpv; ++i) es[i] = 0;  // w=+0, src=0
    }
}

__global__ void convert_x(const float* __restrict__ X, const float* __restrict__ cy,
                          __half* __restrict__ HA, __half* __restrict__ BX) {
    int i = blockIdx.x * blockDim.x + threadIdx.x;
    if (i < NN * DIM / 4) {
        float4 v = ((const float4*)X)[i];
        float c = cy[i >> 4];
        ushort4 a, b;
        a.x = __half_as_ushort(__float2half(v.x));
        a.y = __half_as_ushort(__float2half(v.y));
        a.z = __half_as_ushort(__float2half(v.z));
        a.w = __half_as_ushort(__float2half(v.w));
        b.x = __half_as_ushort(__float2half(v.x * c));
        b.y = __half_as_ushort(__float2half(v.y * c));
        b.z = __half_as_ushort(__float2half(v.z * c));
        b.w = __half_as_ushort(__float2half(v.w * c));
        ((ushort4*)HA)[i] = a;
        ((ushort4*)BX)[i] = b;
    }
}

__device__ __forceinline__ float4 h4f(ushort4 v) {
    return make_float4(__half2float(__ushort_as_half(v.x)),
                       __half2float(__ushort_as_half(v.y)),
                       __half2float(__ushort_as_half(v.z)),
                       __half2float(__ushort_as_half(v.w)));
}

__device__ __forceinline__ float wdec(int r) {
    return __half2float(__ushort_as_half((unsigned short)(((unsigned)r >> 16) & 0xFFFEu)));
}

// One wave per node. sub = lane>>4 (record-pair slot), fl = lane&15 (features
// 4fl..4fl+3). 2-deep pipeline (proven form: 50.5 us, VGPR 16):
// records fetched 2 batches ahead, gathers issued 1 batch ahead.
__global__ void __launch_bounds__(256) step_kernel(
    const __half* __restrict__ Yh, const __half* __restrict__ BX,
    const int* __restrict__ rs, const int* __restrict__ dp,
    const int* __restrict__ es, const float* __restrict__ sc,
    __half* __restrict__ Yho, float* __restrict__ Ffo)
{
    int node = blockIdx.x * 4 + (threadIdx.x >> 6);  // NN % 4 == 0
    int lane = threadIdx.x & 63;
    int sub  = lane >> 4;
    int fl   = lane & 15;
    int un = __builtin_amdgcn_readfirstlane(node);
    int s  = __builtin_amdgcn_readfirstlane(rs[un]);
    int c  = __builtin_amdgcn_readfirstlane(dp[un]);

    const int2* ep = (const int2*)(es + s) + sub;  // ep[4j] = slot's pair of batch j

    float4 acc = make_float4(0.0f, 0.0f, 0.0f, 0.0f);
    int2 rA = ep[0];   // batch 0 pair for this slot
    int2 rB = ep[4];   // batch 1
    ushort4 gA0 = *(const ushort4*)(Yh + (size_t)(rA.x & 0x1FFFF) * DIM + 4 * fl);
    ushort4 gA1 = *(const ushort4*)(Yh + (size_t)(rA.y & 0x1FFFF) * DIM + 4 * fl);
    for (int i = 0; i < c; i += 8) {
        int2 rC = ep[(i >> 1) + 8];  // batch i/8 + 2 (slack-covered)
        ushort4 gB0 = *(const ushort4*)(Yh + (size_t)(rB.x & 0x1FFFF) * DIM + 4 * fl);
        ushort4 gB1 = *(const ushort4*)(Yh + (size_t)(rB.y & 0x1FFFF) * DIM + 4 * fl);
        float w0 = wdec(rA.x);
        float w1 = wdec(rA.y);
        float4 f0 = h4f(gA0), f1 = h4f(gA1);
        acc.x = fmaf(f0.x, w0, acc.x);
        acc.y = fmaf(f0.y, w0, acc.y);
        acc.z = fmaf(f0.z, w0, acc.z);
        acc.w = fmaf(f0.w, w0, acc.w);
        acc.x = fmaf(f1.x, w1, acc.x);
        acc.y = fmaf(f1.y, w1, acc.y);
        acc.z = fmaf(f1.z, w1, acc.z);
        acc.w = fmaf(f1.w, w1, acc.w);
        rA = rB; rB = rC; gA0 = gB0; gA1 = gB1;
    }
    // reduce the 4 record slots (lanes fl, fl+16, fl+32, fl+48)
    acc.x += __shfl_xor(acc.x, 16); acc.x += __shfl_xor(acc.x, 32);
    acc.y += __shfl_xor(acc.y, 16); acc.y += __shfl_xor(acc.y, 32);
    acc.z += __shfl_xor(acc.z, 16); acc.z += __shfl_xor(acc.z, 32);
    acc.w += __shfl_xor(acc.w, 16); acc.w += __shfl_xor(acc.w, 32);

    if (sub == 0) {
        float4 y  = h4f(*(const ushort4*)(Yh + (size_t)un * DIM + 4 * fl));
        float4 bx = h4f(*(const ushort4*)(BX + (size_t)un * DIM + 4 * fl));
        float scl = sc[un];
        float o0 = fmaf(scl, y.x, bx.x) + acc.x;
        float o1 = fmaf(scl, y.y, bx.y) + acc.y;
        float o2 = fmaf(scl, y.z, bx.z) + acc.z;
        float o3 = fmaf(scl, y.w, bx.w) + acc.w;
        if (Ffo) {
            *(float4*)(Ffo + (size_t)un * DIM + 4 * fl) = make_float4(o0, o1, o2, o3);
        } else {
            ushort4 ov;
            ov.x = __half_as_ushort(__float2half(o0));
            ov.y = __half_as_ushort(__float2half(o1));
            ov.z = __half_as_ushort(__float2half(o2));
            ov.w = __half_as_ushort(__float2half(o3));
            *(ushort4*)(Yho + (size_t)un * DIM + 4 * fl) = ov;
        }
    }
}

extern "C" void kernel_launch(void* const* d_in, const int* in_sizes, int n_in,
                              void* d_out, int out_size, void* d_ws, size_t ws_size,
                              hipStream_t stream) {
    const float* x   = (const float*)d_in[0];
    const int* src0  = (const int*)d_in[1];
    const int* dst0  = (const int*)d_in[2];
    const int* src1  = (const int*)d_in[3];
    const int* dst1  = (const int*)d_in[4];
    float* out = (float*)d_out;

    char* ws = (char*)d_ws;
    size_t off = 0;
    auto alloc = [&](size_t bytes) -> void* {
        void* p = ws + off;
        off += (bytes + 255) & ~(size_t)255;
        return p;
    };

    const size_t ES_CAP = (size_t)2 * NE + 8 * NN + 256;  // padded CSR + pipeline slack

    __half* HA   = (__half*)alloc((size_t)NN * DIM * 2);
    __half* HB   = (__half*)alloc((size_t)NN * DIM * 2);
    __half* BX   = (__half*)alloc((size_t)NN * DIM * 2);
    unsigned int* binned = (unsigned int*)alloc((size_t)2 * NE * 4);
    int*    es   = (int*)alloc(ES_CAP * 4);
    int*    blk_cnt  = (int*)alloc((size_t)NBE * NBINS * 4);
    int*    blk_base = (int*)alloc((size_t)NBE * NBINS * 4);
    int*    bin_st   = (int*)alloc((size_t)(NBINS + 1) * 4);
    int*    deg0 = (int*)alloc((size_t)NN * 4);
    int*    deg1 = (int*)alloc((size_t)NN * 4);
    int*    rs   = (int*)alloc((size_t)NN * 4);
    int*    dp   = (int*)alloc((size_t)NN * 4);
    float2* nsc  = (float2*)alloc((size_t)NN * 8);
    float*  sc   = (float*)alloc((size_t)NN * 4);
    float*  cy   = (float*)alloc((size_t)NN * 4);
    int*    bs   = (int*)alloc((size_t)NBLK * 4);

    const int TB = 256;
    bin_count<<<NBE, 256, 0, stream>>>(dst0, dst1, blk_cnt);
    bin_scan<<<1, 512, 0, stream>>>(blk_cnt, bin_st);
    blk_base_k<<<NBINS, NBE, 0, stream>>>(blk_cnt, bin_st, blk_base);
    bin_permute<<<NBE, 256, 0, stream>>>(src0, dst0, src1, dst1, blk_base, binned);
    deg_count<<<NBINS, 256, 0, stream>>>(binned, bin_st, deg0, deg1);
    scan_l1<<<NBLK, 256, 0, stream>>>(deg0, deg1, rs, dp, bs);
    scan_l2<<<1, 512, 0, stream>>>(bs);
    scan_l3<<<NBLK, 256, 0, stream>>>(rs, bs);
    node_params<<<(NN + TB - 1) / TB, TB, 0, stream>>>(deg0, deg1, nsc, sc, cy);
    csr_scatter<<<NBINS, 256, 0, stream>>>(binned, bin_st, rs, deg0, deg1, nsc, es);
    convert_x<<<(NN * DIM / 4 + TB - 1) / TB, TB, 0, stream>>>(x, cy, HA, BX);

    int grid = NN / 4;
    for (int i = 0; i < 8; ++i) {
        const __half* hin = (i & 1) ? HB : HA;
        __half* hout = (i & 1) ? HA : HB;
        float* fout = (i == 7) ? out : nullptr;
        step_kernel<<<grid, TB, 0, stream>>>(hin, BX, rs, dp, es, sc, hout, fout);
    }
}